// Round 6
// baseline (144.691 us; speedup 1.0000x reference)
//
#include <hip/hip_runtime.h>
#include <math.h>

#define BB 32
#define CC 256
#define NN 1024
#define THR 8.0f

typedef unsigned short u16;
typedef unsigned int u32;
typedef u16 u16x8 __attribute__((ext_vector_type(8)));
typedef _Float16 h16;
typedef h16 h16x8 __attribute__((ext_vector_type(8)));
typedef float f32x4 __attribute__((ext_vector_type(4)));
typedef float f32x16 __attribute__((ext_vector_type(16)));
typedef u32 u32x4v __attribute__((ext_vector_type(4)));

__device__ __forceinline__ h16x8 ldh8(const u16* p) {
    return __builtin_bit_cast(h16x8, *(const u16x8*)p);
}
__device__ __forceinline__ f32x4 mfma16(h16x8 a, h16x8 b, f32x4 c) {
    return __builtin_amdgcn_mfma_f32_16x16x32_f16(a, b, c, 0, 0, 0);
}
__device__ __forceinline__ f32x16 mfma32(h16x8 a, h16x8 b, f32x16 c) {
    return __builtin_amdgcn_mfma_f32_32x32x16_f16(a, b, c, 0, 0, 0);
}
__device__ __forceinline__ u32 pkrtz(float a, float b) {
    return __builtin_bit_cast(u32, __builtin_amdgcn_cvt_pkrtz(a, b));
}
// async global->LDS, 16B/lane: dst = wave-uniform base + lane*16 (linear)
__device__ __forceinline__ void gll16(const void* g, void* l) {
    __builtin_amdgcn_global_load_lds((const __attribute__((address_space(1))) u32*)g,
                                     (__attribute__((address_space(3))) u32*)l, 16, 0, 0);
}

// ---------------------------------------------------------------------------
// Kernel 0: W f32 [256][256] -> fragment-major fp16 whf (16x16 A-frag slots).
// ---------------------------------------------------------------------------
__global__ __launch_bounds__(256) void k_wprep(const float* __restrict__ w,
                                               u16* __restrict__ whf) {
    int s = blockIdx.x * 256 + threadIdx.x;  // 8192 slots
    int ot = s >> 9, ks = (s >> 6) & 7, l = s & 63;
    const float* src = w + (size_t)(ot * 16 + (l & 15)) * CC + ks * 32 + 8 * (l >> 4);
    float4 a = *(const float4*)src;
    float4 c = *(const float4*)(src + 4);
    u32x4v o = (u32x4v){pkrtz(a.x, a.y), pkrtz(a.z, a.w), pkrtz(c.x, c.y), pkrtz(c.z, c.w)};
    *(u32x4v*)(whf + (size_t)s * 8) = o;
}

// ---------------------------------------------------------------------------
// Kernel 1: per (b, 32-p tile): emit kf (32x32 Q/K-frag-major fp16 of X^T) AND
// V = W@X + b into vf (32x32 PV-frag-major fp16). Double-buffered x loads.
// kf slot: kf[((b*32+it)*16 + ks)*64 + l]*8+e = X^T[b][it*32+(l&31)][ks*16+8*(l>>5)+e]
// vf slot: vf[(((b*32+jt)*8 + oc)*2 + ksl)*64 + l]*8+e
//          = V[b][oc*32+(l&31)][jt*32 + ksl*16 + 8*(l>>5)+e]
// ---------------------------------------------------------------------------
__global__ __launch_bounds__(256, 4) void k_xform(const float* __restrict__ x,
                                                  const u16* __restrict__ whf,
                                                  const float* __restrict__ bias,
                                                  u16* __restrict__ kf,
                                                  u16* __restrict__ vf) {
    __shared__ __align__(16) float xs[32][68];    // [p][c-chunk], 8704 B
    __shared__ __align__(16) u16 Vs[4][64 * 40];  // per-wave [64 o][40 j]
    int bid = blockIdx.x;
    int b = bid >> 5, pt = bid & 31;
    int t = threadIdx.x, wave = t >> 6, lane = t & 63;
    int l15 = lane & 15, l4 = lane >> 4, l31 = lane & 31, lh = lane >> 5;
    int p0 = pt * 32;
    int r0 = t >> 3, pq = (t & 7) * 4;

    f32x4 acc[4][2];
#pragma unroll
    for (int m = 0; m < 4; ++m)
#pragma unroll
        for (int n = 0; n < 2; ++n) acc[m][n] = (f32x4){0.f, 0.f, 0.f, 0.f};

    float4 lv0 = *(const float4*)(x + (size_t)(b * CC + r0) * NN + p0 + pq);
    float4 lv1 = *(const float4*)(x + (size_t)(b * CC + 32 + r0) * NN + p0 + pq);

    for (int cc = 0; cc < 4; ++cc) {
        xs[pq + 0][r0] = lv0.x; xs[pq + 1][r0] = lv0.y;
        xs[pq + 2][r0] = lv0.z; xs[pq + 3][r0] = lv0.w;
        xs[pq + 0][r0 + 32] = lv1.x; xs[pq + 1][r0 + 32] = lv1.y;
        xs[pq + 2][r0 + 32] = lv1.z; xs[pq + 3][r0 + 32] = lv1.w;
        __syncthreads();
        if (cc < 3) {  // prefetch next chunk (hides under compute below)
            lv0 = *(const float4*)(x + (size_t)(b * CC + (cc + 1) * 64 + r0) * NN + p0 + pq);
            lv1 = *(const float4*)(x + (size_t)(b * CC + (cc + 1) * 64 + 32 + r0) * NN + p0 + pq);
        }
        // kf slot write: ks = cc*4 + wave, this thread -> slot lane
        {
            const float* sp = &xs[l31][wave * 16 + 8 * lh];
            f32x4 a = *(const f32x4*)sp;
            f32x4 c2 = *(const f32x4*)(sp + 4);
            u32x4v o = (u32x4v){pkrtz(a[0], a[1]), pkrtz(a[2], a[3]),
                                pkrtz(c2[0], c2[1]), pkrtz(c2[2], c2[3])};
            *(u32x4v*)(kf + ((size_t)((b * 32 + pt) * 16 + cc * 4 + wave) * 64 + lane) * 8) = o;
        }
        // GEMM: 2 k32-steps per chunk
#pragma unroll
        for (int ksl = 0; ksl < 2; ++ksl) {
            int ks = cc * 2 + ksl;
            h16x8 afr[4], bfr[2];
#pragma unroll
            for (int m = 0; m < 4; ++m)
                afr[m] = ldh8(whf + (size_t)(((wave * 4 + m) * 8 + ks) * 64 + lane) * 8);
#pragma unroll
            for (int n = 0; n < 2; ++n) {
                const float* sp = &xs[n * 16 + l15][ksl * 32 + 8 * l4];
                f32x4 w0 = *(const f32x4*)sp;
                f32x4 w1 = *(const f32x4*)(sp + 4);
                u32x4v tv = (u32x4v){pkrtz(w0[0], w0[1]), pkrtz(w0[2], w0[3]),
                                     pkrtz(w1[0], w1[1]), pkrtz(w1[2], w1[3])};
                bfr[n] = __builtin_bit_cast(h16x8, tv);
            }
#pragma unroll
            for (int m = 0; m < 4; ++m)
#pragma unroll
                for (int n = 0; n < 2; ++n) acc[m][n] = mfma16(afr[m], bfr[n], acc[m][n]);
        }
        __syncthreads();
    }

    // epilogue: bias + transpose through per-wave LDS -> vf frag slots
    u16* Vsw = &Vs[wave][0];  // [64 o][40]
#pragma unroll
    for (int m = 0; m < 4; ++m) {
#pragma unroll
        for (int r = 0; r < 4; ++r) {
            int ol = m * 16 + 4 * l4 + r;
            float bv = bias[wave * 64 + ol];
#pragma unroll
            for (int n = 0; n < 2; ++n)
                Vsw[ol * 40 + n * 16 + l15] =
                    __builtin_bit_cast(u16, (h16)(acc[m][n][r] + bv));
        }
    }
#pragma unroll
    for (int ocs = 0; ocs < 2; ++ocs) {
#pragma unroll
        for (int ksl = 0; ksl < 2; ++ksl) {
            u16x8 v = *(u16x8*)&Vsw[(ocs * 32 + l31) * 40 + ksl * 16 + 8 * lh];
            *(u16x8*)(vf + ((((size_t)(b * 32 + pt) * 8 + wave * 2 + ocs) * 2 + ksl) * 64 +
                            lane) * 8) = v;
        }
    }
}

// ---------------------------------------------------------------------------
// Kernel 2: flash attention, 32x32x16 MFMA. Block = 64 i rows, 4 waves =
// 2 rg (i-halves) x 2 jg (j-halves, exact combine). K from frag-major kf via
// linear gll double-buffer (1 barrier/it); V per-oc from frag-major vf (L1);
// P packed in-register (cvt_pkrtz + permlane32_swap, R4-verified); epilogue:
// lane-local 2x2 maxpool -> LDS -> one contiguous 16KB store per block.
// ---------------------------------------------------------------------------
__global__ __launch_bounds__(256, 2) void k_attn(const u16* __restrict__ kf,
                                                 const u16* __restrict__ vf,
                                                 float* __restrict__ out) {
    __shared__ __align__(16) char smem[66560];
    // Kb: [jg][buf] 16KB each at jg*32768 + buf*16384; Mx/Lx at 65536/66048.
    float* Mx = (float*)(smem + 65536);
    float* Lx = (float*)(smem + 66048);

    int bid = blockIdx.x;
    int xcd = bid & 7, s0 = bid >> 3;
    int b = xcd * 4 + (s0 >> 4);
    int i0 = (s0 & 15) * 64;
    int t = threadIdx.x, wave = t >> 6, lane = t & 63;
    int rg = wave & 1, jg = wave >> 1;
    int l31 = lane & 31, lh = lane >> 5;
    const u16* kfb = kf + (size_t)b * NN * CC;
    const u16* vfb = vf + (size_t)b * NN * CC;

    // Q B-frags: lane holds col i = itq*32 + l31, k = 16*ks + 8*lh + e
    h16x8 qfr[16];
    {
        int itq = (i0 >> 5) + rg;
#pragma unroll
        for (int ks = 0; ks < 16; ++ks)
            qfr[ks] = ldh8(kfb + ((size_t)(itq * 16 + ks) * 64 + lane) * 8);
    }

    // prologue: stage K tile jg*16 into buf0 (linear frag-major copy)
    {
        int tile = jg * 16;
#pragma unroll
        for (int inst = 0; inst < 8; ++inst) {
            int sl = rg * 8 + inst;
            gll16(kfb + ((size_t)(tile * 16 + sl) * 64 + lane) * 8,
                  smem + jg * 32768 + sl * 1024);
        }
    }

    f32x16 oacc[8];
#pragma unroll
    for (int oc = 0; oc < 8; ++oc)
#pragma unroll
        for (int r = 0; r < 16; ++r) oacc[oc][r] = 0.f;
    float m = -INFINITY, l = 0.f;
    __syncthreads();

    for (int it = 0; it < 16; ++it) {
        int cur = it & 1;
        int jt = jg * 16 + it;
        const u16* KbC = (const u16*)(smem + jg * 32768 + cur * 16384);
        if (it < 15) {  // async prefetch next K tile into other buffer
            int tile = jt + 1;
#pragma unroll
            for (int inst = 0; inst < 8; ++inst) {
                int sl = rg * 8 + inst;
                gll16(kfb + ((size_t)(tile * 16 + sl) * 64 + lane) * 8,
                      smem + jg * 32768 + (cur ^ 1) * 16384 + sl * 1024);
            }
        }
        // QK^T swapped: S[j=crow(r,lh)][i=l31]
        f32x16 s;
#pragma unroll
        for (int r = 0; r < 16; ++r) s[r] = 0.f;
        __builtin_amdgcn_s_setprio(1);
#pragma unroll
        for (int ks = 0; ks < 16; ++ks) {
            h16x8 a = ldh8(KbC + (ks * 64 + lane) * 8);
            s = mfma32(a, qfr[ks], s);
        }
        __builtin_amdgcn_s_setprio(0);

        // lane-local online softmax (col i = l31; rows split across lh)
        float mx = s[0];
#pragma unroll
        for (int r = 1; r < 16; ++r) mx = fmaxf(mx, s[r]);
        mx = fmaxf(mx, __shfl_xor(mx, 32));
        if (__any(mx > m + THR)) {
            float mn = fmaxf(m, mx);
            float f = __expf(m - mn);
            m = mn;
            l *= f;
#pragma unroll
            for (int oc = 0; oc < 8; ++oc)
#pragma unroll
                for (int r = 0; r < 16; ++r) oacc[oc][r] *= f;
        }
        float p[16], rs = 0.f;
#pragma unroll
        for (int r = 0; r < 16; ++r) { p[r] = __expf(s[r] - m); rs += p[r]; }
        rs += __shfl_xor(rs, 32);
        l += rs;

        // pack P -> fp16 B-frags in-register (R4-verified)
        u32 pk0 = pkrtz(p[0], p[1]), pk1 = pkrtz(p[2], p[3]);
        u32 pk2 = pkrtz(p[4], p[5]), pk3 = pkrtz(p[6], p[7]);
        u32 pk4 = pkrtz(p[8], p[9]), pk5 = pkrtz(p[10], p[11]);
        u32 pk6 = pkrtz(p[12], p[13]), pk7 = pkrtz(p[14], p[15]);
        asm volatile("v_permlane32_swap_b32 %0, %1" : "+v"(pk0), "+v"(pk2));
        asm volatile("v_permlane32_swap_b32 %0, %1" : "+v"(pk1), "+v"(pk3));
        asm volatile("v_permlane32_swap_b32 %0, %1" : "+v"(pk4), "+v"(pk6));
        asm volatile("v_permlane32_swap_b32 %0, %1" : "+v"(pk5), "+v"(pk7));
        h16x8 pa0 = __builtin_bit_cast(h16x8, (u32x4v){pk0, pk1, pk2, pk3});
        h16x8 pa1 = __builtin_bit_cast(h16x8, (u32x4v){pk4, pk5, pk6, pk7});

        // PV: O[o][i] += V[o][j] P[j][i]; V per-oc from L1 with 1-ahead prefetch
        const u16* vt = vfb + (size_t)jt * 8192;
        u16x8 v0n = *(const u16x8*)(vt + lane * 8);
        u16x8 v1n = *(const u16x8*)(vt + 512 + lane * 8);
        __builtin_amdgcn_s_setprio(1);
#pragma unroll
        for (int oc = 0; oc < 8; ++oc) {
            u16x8 v0 = v0n, v1 = v1n;
            if (oc < 7) {
                v0n = *(const u16x8*)(vt + (size_t)((oc + 1) * 2) * 512 + lane * 8);
                v1n = *(const u16x8*)(vt + (size_t)((oc + 1) * 2 + 1) * 512 + lane * 8);
            }
            oacc[oc] = mfma32(__builtin_bit_cast(h16x8, v0), pa0, oacc[oc]);
            oacc[oc] = mfma32(__builtin_bit_cast(h16x8, v1), pa1, oacc[oc]);
        }
        __builtin_amdgcn_s_setprio(0);
        __syncthreads();  // drains gll prefetch; frees buf cur
    }

    // ---- combine j-halves (exact): partner wave = wave^2
    if (lane < 32) {
        Mx[wave * 32 + l31] = m;
        Lx[wave * 32 + l31] = l;
    }
    float* Ob = (float*)smem;  // 64KB raw-frag buffer (Kb area free)
    if (jg == 1) {
#pragma unroll
        for (int oc = 0; oc < 8; ++oc)
#pragma unroll
            for (int q = 0; q < 4; ++q) {
                f32x4 v = (f32x4){oacc[oc][4 * q + 0], oacc[oc][4 * q + 1],
                                  oacc[oc][4 * q + 2], oacc[oc][4 * q + 3]};
                *(f32x4*)&Ob[(((rg * 8 + oc) * 4 + q) * 64 + lane) * 4] = v;
            }
    }
    __syncthreads();
    if (jg == 0) {
        int pidx = (wave ^ 2) * 32 + l31;
        float m2 = Mx[pidx], l2 = Lx[pidx];
        float ms = fmaxf(m, m2);
        float f0 = __expf(m - ms), f1 = __expf(m2 - ms);
        float inv = 1.f / (l * f0 + l2 * f1);
        f0 *= inv; f1 *= inv;
#pragma unroll
        for (int oc = 0; oc < 8; ++oc)
#pragma unroll
            for (int q = 0; q < 4; ++q) {
                f32x4 o1 = *(const f32x4*)&Ob[(((rg * 8 + oc) * 4 + q) * 64 + lane) * 4];
#pragma unroll
                for (int e = 0; e < 4; ++e)
                    oacc[oc][4 * q + e] = oacc[oc][4 * q + e] * f0 + o1[e] * f1;
            }
    }
    __syncthreads();  // Ob free -> PoolBuf overlays
    float* PoolBuf = (float*)smem;  // [64 i][68]
    if (jg == 0) {
        // lane holds i = i0 + rg*32 + l31; o = oc*32 + (r&3)+8*(r>>2)+4*lh.
        // pool over o bits {0,5} (lane-local): slot = (o>>6)*16 + pw,
        // pw = (r>>2)*4 + lh*2 + ((r>>1)&1)
        int il = rg * 32 + l31;
#pragma unroll
        for (int oc2 = 0; oc2 < 4; ++oc2)
#pragma unroll
            for (int q = 0; q < 4; ++q)
#pragma unroll
                for (int b1 = 0; b1 < 2; ++b1) {
                    int r = 4 * q + 2 * b1;
                    float v = fmaxf(fmaxf(oacc[2 * oc2][r], oacc[2 * oc2][r + 1]),
                                    fmaxf(oacc[2 * oc2 + 1][r], oacc[2 * oc2 + 1][r + 1]));
                    PoolBuf[il * 68 + oc2 * 16 + q * 4 + lh * 2 + b1] = v;
                }
    }
    __syncthreads();
    // coalesced store: block output = 16 channels x 256 = one contiguous 16KB
    {
        float* ob = out + ((size_t)b * 256 + (i0 >> 2)) * 256;
        int row = t >> 2, cb = (t & 3) * 16;
#pragma unroll
        for (int e = 0; e < 4; ++e) {
            f32x4 vv = *(f32x4*)&PoolBuf[row * 68 + cb + e * 4];
            *(f32x4*)&ob[row * 64 + cb + e * 4] = vv;
        }
    }
}

// ---------------------------------------------------------------------------
extern "C" void kernel_launch(void* const* d_in, const int* in_sizes, int n_in,
                              void* d_out, int out_size, void* d_ws, size_t ws_size,
                              hipStream_t stream) {
    const float* x = (const float*)d_in[0];
    const float* w = (const float*)d_in[1];
    const float* bias = (const float*)d_in[2];
    float* out = (float*)d_out;
    u16* kf = (u16*)d_ws;                   // [32][32 it][16 ks][64][8] fp16
    u16* vf = kf + (size_t)BB * NN * CC;    // [32][32 jt][8 oc][2][64][8] fp16
    u16* whf = vf + (size_t)BB * NN * CC;   // fragment-major W
    k_wprep<<<32, 256, 0, stream>>>(w, whf);
    k_xform<<<1024, 256, 0, stream>>>(x, whf, bias, kf, vf);
    k_attn<<<512, 256, 0, stream>>>(kf, vf, out);
}